// Round 1
// baseline (632.022 us; speedup 1.0000x reference)
//
#include <hip/hip_runtime.h>

#define DIM_IN 128
#define DIM_HID 64

// ---------------- degree / normalization ----------------

__global__ void init_deg_kernel(float* __restrict__ deg, int n) {
    int i = blockIdx.x * 256 + threadIdx.x;
    if (i < n) deg[i] = 1.0f;  // self-loop contributes 1
}

__global__ void count_deg_kernel(const int* __restrict__ dst, float* __restrict__ deg, int E) {
    int e = blockIdx.x * 256 + threadIdx.x;
    if (e < E) atomicAdd(&deg[dst[e]], 1.0f);
}

__global__ void dinv_kernel(float* __restrict__ deg, int n) {
    int i = blockIdx.x * 256 + threadIdx.x;
    if (i < n) deg[i] = rsqrtf(deg[i]);  // deg >= 1 always (self-loops)
}

// ---------------- bias init (accumulator = bias, then scatter-add) ----------------

__global__ void bias_init_kernel(float* __restrict__ out, const float* __restrict__ b, int total) {
    int i = blockIdx.x * 256 + threadIdx.x;
    if (i < total) out[i] = b[i & 63];
}

// ---------------- dense h = [relu](x) @ W   (K = 128 or 64, 64 output cols) ----------------

template <int K, bool RELU>
__launch_bounds__(256)
__global__ void gemm_kernel(const float* __restrict__ x, const float* __restrict__ W,
                            float* __restrict__ out, int n) {
    __shared__ float xs[16 * K];
    const int tid  = threadIdx.x;
    const int row0 = blockIdx.x * 16;
    constexpr int K4 = K / 4;

    const float4* x4  = (const float4*)x;
    float4*       xs4 = (float4*)xs;
    for (int i = tid; i < 16 * K4; i += 256) {
        int r   = i / K4;
        int c   = i - r * K4;
        int row = row0 + r;
        xs4[i] = (row < n) ? x4[(size_t)row * K4 + c] : make_float4(0.f, 0.f, 0.f, 0.f);
    }
    __syncthreads();

    const int col = tid & 63;   // wave-wide: 64 consecutive cols -> coalesced W reads
    const int r0  = tid >> 6;   // 0..3 ; each thread does rows r0, r0+4, r0+8, r0+12

    float acc0 = 0.f, acc1 = 0.f, acc2 = 0.f, acc3 = 0.f;
    for (int k = 0; k < K; ++k) {
        float w  = W[k * 64 + col];
        float v0 = xs[(r0 + 0)  * K + k];   // LDS broadcast within wave
        float v1 = xs[(r0 + 4)  * K + k];
        float v2 = xs[(r0 + 8)  * K + k];
        float v3 = xs[(r0 + 12) * K + k];
        if (RELU) {
            v0 = fmaxf(v0, 0.f); v1 = fmaxf(v1, 0.f);
            v2 = fmaxf(v2, 0.f); v3 = fmaxf(v3, 0.f);
        }
        acc0 = fmaf(v0, w, acc0);
        acc1 = fmaf(v1, w, acc1);
        acc2 = fmaf(v2, w, acc2);
        acc3 = fmaf(v3, w, acc3);
    }

    int row = row0 + r0;
    if (row      < n) out[(size_t)row        * 64 + col] = acc0;
    if (row + 4  < n) out[(size_t)(row + 4)  * 64 + col] = acc1;
    if (row + 8  < n) out[(size_t)(row + 8)  * 64 + col] = acc2;
    if (row + 12 < n) out[(size_t)(row + 12) * 64 + col] = acc3;
}

// ---------------- edge scatter: out[dst] += h[src] * dinv[src]*dinv[dst] ----------------
// one wave per edge, lane = feature (64 features). Edges e in [0, E+n):
// e < E -> real edge, else self-loop of node (e - E).

__global__ void scatter_kernel(const int* __restrict__ src, const int* __restrict__ dst,
                               const float* __restrict__ dinv, const float* __restrict__ h,
                               float* __restrict__ out, int E, int n) {
    int e = blockIdx.x * 4 + (threadIdx.x >> 6);
    if (e >= E + n) return;
    int lane = threadIdx.x & 63;
    int s, d;
    if (e < E) { s = src[e]; d = dst[e]; }
    else       { s = e - E; d = s; }
    float norm = dinv[s] * dinv[d];           // wave-uniform
    float v = h[(size_t)s * 64 + lane] * norm; // coalesced 256B gather
    atomicAdd(&out[(size_t)d * 64 + lane], v); // coalesced 64-dword scatter
}

// ---------------- launch ----------------

extern "C" void kernel_launch(void* const* d_in, const int* in_sizes, int n_in,
                              void* d_out, int out_size, void* d_ws, size_t ws_size,
                              hipStream_t stream) {
    const float* x   = (const float*)d_in[0];
    const int*   ei  = (const int*)d_in[1];   // int64 demoted to int32 by default JAX config
    const float* W1  = (const float*)d_in[2];
    const float* b1  = (const float*)d_in[3];
    const float* W2  = (const float*)d_in[4];
    const float* b2  = (const float*)d_in[5];
    float*       out = (float*)d_out;

    const int n = in_sizes[0] / DIM_IN;   // 100000
    const int E = in_sizes[1] / 2;        // 1000000
    const int* srcp = ei;
    const int* dstp = ei + E;

    // workspace layout (floats): dinv[npad] | h[n*64] | agg[n*64]
    const int npad = ((n + 255) / 256) * 256;
    float* dinv = (float*)d_ws;
    float* h    = dinv + npad;
    float* agg  = h + (size_t)n * 64;

    const int nb  = (n + 255) / 256;
    const int eb  = (E + 255) / 256;
    const int fb  = (n * 64 + 255) / 256;
    const int gb  = (n + 15) / 16;
    const int sb  = (E + n + 3) / 4;

    // normalization (shared by both layers)
    init_deg_kernel<<<nb, 256, 0, stream>>>(dinv, n);
    count_deg_kernel<<<eb, 256, 0, stream>>>(dstp, dinv, E);
    dinv_kernel<<<nb, 256, 0, stream>>>(dinv, n);

    // layer 1: h = x @ W1 ; agg = b1 + scatter(h)
    gemm_kernel<DIM_IN, false><<<gb, 256, 0, stream>>>(x, W1, h, n);
    bias_init_kernel<<<fb, 256, 0, stream>>>(agg, b1, n * 64);
    scatter_kernel<<<sb, 256, 0, stream>>>(srcp, dstp, dinv, h, agg, E, n);

    // layer 2: h = relu(agg) @ W2 ; out = b2 + scatter(h)
    gemm_kernel<DIM_HID, true><<<gb, 256, 0, stream>>>(agg, W2, h, n);
    bias_init_kernel<<<fb, 256, 0, stream>>>(out, b2, n * 64);
    scatter_kernel<<<sb, 256, 0, stream>>>(srcp, dstp, dinv, h, out, E, n);
}

// Round 2
// 317.594 us; speedup vs baseline: 1.9900x; 1.9900x over previous
//
#include <hip/hip_runtime.h>

#define DIM_IN 128
#define DIM_HID 64

// ---------------- degree count (int) ----------------

__global__ void count_deg_kernel(const int* __restrict__ dst, int* __restrict__ cnt, int E) {
    int e = blockIdx.x * 256 + threadIdx.x;
    if (e < E) atomicAdd(&cnt[dst[e]], 1);
}

__global__ void dinv_kernel(const int* __restrict__ cnt, float* __restrict__ dinv, int n) {
    int i = blockIdx.x * 256 + threadIdx.x;
    if (i < n) dinv[i] = rsqrtf((float)(cnt[i] + 1));  // +1 self-loop
}

// ---------------- CSR alloc: rowptr[i] = running offset of bucket i ----------------
// Per-block inclusive scan + single atomic bump per block. Buckets are disjoint,
// so non-deterministic block order is harmless.

__global__ void alloc_kernel(const int* __restrict__ cnt, int* __restrict__ rowptr,
                             int* __restrict__ alloc, int n) {
    __shared__ int sc[256];
    __shared__ int base;
    int i = blockIdx.x * 256 + threadIdx.x;
    int v = (i < n) ? cnt[i] : 0;
    sc[threadIdx.x] = v;
    __syncthreads();
    for (int off = 1; off < 256; off <<= 1) {
        int t = (threadIdx.x >= off) ? sc[threadIdx.x - off] : 0;
        __syncthreads();
        sc[threadIdx.x] += t;
        __syncthreads();
    }
    if (threadIdx.x == 255) base = atomicAdd(alloc, sc[255]);
    __syncthreads();
    if (i < n) rowptr[i] = base + sc[threadIdx.x] - v;  // exclusive within block + block base
}

__global__ void fill_kernel(const int* __restrict__ src, const int* __restrict__ dst,
                            const int* __restrict__ rowptr, int* __restrict__ cur,
                            int* __restrict__ srcs, int E) {
    int e = blockIdx.x * 256 + threadIdx.x;
    if (e < E) {
        int d = dst[e];
        int pos = rowptr[d] + atomicAdd(&cur[d], 1);
        srcs[pos] = src[e];
    }
}

// ---------------- dense hs = [relu](x) @ W * dinv[row] ----------------

template <int K, bool RELU>
__launch_bounds__(256)
__global__ void gemm_kernel(const float* __restrict__ x, const float* __restrict__ W,
                            const float* __restrict__ dinv, float* __restrict__ out, int n) {
    __shared__ float xs[16 * K];
    const int tid  = threadIdx.x;
    const int row0 = blockIdx.x * 16;
    constexpr int K4 = K / 4;

    const float4* x4  = (const float4*)x;
    float4*       xs4 = (float4*)xs;
    for (int i = tid; i < 16 * K4; i += 256) {
        int r   = i / K4;
        int c   = i - r * K4;
        int row = row0 + r;
        xs4[i] = (row < n) ? x4[(size_t)row * K4 + c] : make_float4(0.f, 0.f, 0.f, 0.f);
    }
    __syncthreads();

    const int col = tid & 63;
    const int r0  = tid >> 6;

    float acc0 = 0.f, acc1 = 0.f, acc2 = 0.f, acc3 = 0.f;
    for (int k = 0; k < K; ++k) {
        float w  = W[k * 64 + col];
        float v0 = xs[(r0 + 0)  * K + k];
        float v1 = xs[(r0 + 4)  * K + k];
        float v2 = xs[(r0 + 8)  * K + k];
        float v3 = xs[(r0 + 12) * K + k];
        if (RELU) {
            v0 = fmaxf(v0, 0.f); v1 = fmaxf(v1, 0.f);
            v2 = fmaxf(v2, 0.f); v3 = fmaxf(v3, 0.f);
        }
        acc0 = fmaf(v0, w, acc0);
        acc1 = fmaf(v1, w, acc1);
        acc2 = fmaf(v2, w, acc2);
        acc3 = fmaf(v3, w, acc3);
    }

    int row = row0 + r0;
    if (row      < n) out[(size_t)row        * 64 + col] = acc0 * dinv[row];
    if (row + 4  < n) out[(size_t)(row + 4)  * 64 + col] = acc1 * dinv[row + 4];
    if (row + 8  < n) out[(size_t)(row + 8)  * 64 + col] = acc2 * dinv[row + 8];
    if (row + 12 < n) out[(size_t)(row + 12) * 64 + col] = acc3 * dinv[row + 12];
}

// ---------------- pull aggregation: out[d] = dinv[d]*(sum_{s in N(d)} hs[s] + hs[d]) + b ----------------
// one wave per node, lane = feature.

__global__ void gather_kernel(const int* __restrict__ rowptr, const int* __restrict__ cnt,
                              const int* __restrict__ srcs, const float* __restrict__ dinv,
                              const float* __restrict__ hs, const float* __restrict__ b,
                              float* __restrict__ out, int n) {
    int node = blockIdx.x * 4 + (threadIdx.x >> 6);
    if (node >= n) return;
    int lane  = threadIdx.x & 63;
    int start = rowptr[node];
    int c     = cnt[node];

    float acc = hs[(size_t)node * 64 + lane];  // self-loop term
    int j = 0;
    for (; j + 2 <= c; j += 2) {
        int s0 = srcs[start + j];
        int s1 = srcs[start + j + 1];
        float v0 = hs[(size_t)s0 * 64 + lane];
        float v1 = hs[(size_t)s1 * 64 + lane];
        acc += v0;
        acc += v1;
    }
    if (j < c) acc += hs[(size_t)srcs[start + j] * 64 + lane];

    out[(size_t)node * 64 + lane] = acc * dinv[node] + b[lane];
}

// ---------------- launch ----------------

extern "C" void kernel_launch(void* const* d_in, const int* in_sizes, int n_in,
                              void* d_out, int out_size, void* d_ws, size_t ws_size,
                              hipStream_t stream) {
    const float* x   = (const float*)d_in[0];
    const int*   ei  = (const int*)d_in[1];   // int64 demoted to int32 by JAX default config
    const float* W1  = (const float*)d_in[2];
    const float* b1  = (const float*)d_in[3];
    const float* W2  = (const float*)d_in[4];
    const float* b2  = (const float*)d_in[5];
    float*       out = (float*)d_out;

    const int n = in_sizes[0] / DIM_IN;   // 100000
    const int E = in_sizes[1] / 2;        // 1000000
    const int* srcp = ei;
    const int* dstp = ei + E;

    const int npad = ((n + 255) / 256) * 256;
    const int Epad = ((E + 255) / 256) * 256;

    // workspace layout (4B units):
    int*   cnt    = (int*)d_ws;            // npad
    int*   cur    = cnt + npad;            // npad
    int*   alloc  = cur + npad;            // 256
    int*   rowptr = alloc + 256;           // npad
    float* dinv   = (float*)(rowptr + npad); // npad
    int*   srcs   = (int*)(dinv + npad);   // Epad
    float* h      = (float*)(srcs + Epad); // n*64
    float* agg    = h + (size_t)n * 64;    // n*64

    const int nb = (n + 255) / 256;
    const int eb = (E + 255) / 256;
    const int gb = (n + 15) / 16;
    const int ab = (n + 3) / 4;

    // zero cnt, cur, alloc in one memset
    hipMemsetAsync(cnt, 0, (size_t)(2 * npad + 256) * 4, stream);

    // normalization + CSR build (shared by both layers)
    count_deg_kernel<<<eb, 256, 0, stream>>>(dstp, cnt, E);
    dinv_kernel<<<nb, 256, 0, stream>>>(cnt, dinv, n);
    alloc_kernel<<<nb, 256, 0, stream>>>(cnt, rowptr, alloc, n);
    fill_kernel<<<eb, 256, 0, stream>>>(srcp, dstp, rowptr, cur, srcs, E);

    // layer 1: h = (x @ W1) * dinv ; agg = dinv*(gather + self) + b1
    gemm_kernel<DIM_IN, false><<<gb, 256, 0, stream>>>(x, W1, dinv, h, n);
    gather_kernel<<<ab, 256, 0, stream>>>(rowptr, cnt, srcs, dinv, h, b1, agg, n);

    // layer 2: h = (relu(agg) @ W2) * dinv ; out = dinv*(gather + self) + b2
    gemm_kernel<DIM_HID, true><<<gb, 256, 0, stream>>>(agg, W2, dinv, h, n);
    gather_kernel<<<ab, 256, 0, stream>>>(rowptr, cnt, srcs, dinv, h, b2, out, n);
}